// Round 1
// baseline (537.630 us; speedup 1.0000x reference)
//
#include <hip/hip_runtime.h>
#include <hip/hip_bf16.h>
#include <cstdint>

#define DI __device__ __forceinline__

typedef __attribute__((ext_vector_type(4))) float f32x4;
typedef __attribute__((ext_vector_type(8))) short bf16x8;

static constexpr int B_ = 16384, I_ = 1024, H_ = 1024;
static constexpr int M = B_;          // 16384 rows
static constexpr int N = 4 * H_;      // 4096 gate-cols (f,i,k,o × 1024)
static constexpr int K = I_ + H_;     // 2048 ([x | h] concatenated)

// workspace layout (bytes)
static constexpr size_t OFF_A  = 0;                        // M*K bf16   (64 MB)
static constexpr size_t OFF_W  = OFF_A + (size_t)M * K * 2; // N*K bf16  (16 MB)
static constexpr size_t OFF_BI = OFF_W + (size_t)N * K * 2; // N f32     (16 KB)
static constexpr size_t OFF_G  = OFF_BI + (size_t)N * 4;    // M*N bf16  (128 MB)

DI unsigned short f2bf(float f) {
    union { float f; unsigned u; } v; v.f = f;
    unsigned r = v.u + 0x7FFFu + ((v.u >> 16) & 1u);  // round-to-nearest-even
    return (unsigned short)(r >> 16);
}
DI float bf2f(unsigned short u) {
    union { unsigned u; float f; } v; v.u = ((unsigned)u) << 16; return v.f;
}

// ---------------------------------------------------------------- convert
// Builds A' = [x | h] (M x K) and W' = [Wx | Wh] (N x K) in bf16.
// 4 cols per thread, float4 read / ushort4 write. Rows: M for A, then N for W.
__global__ void cvt_kernel(const float* __restrict__ x, const float* __restrict__ h,
                           const float* __restrict__ Wx, const float* __restrict__ Wh,
                           unsigned short* __restrict__ A, unsigned short* __restrict__ W)
{
    long tid = (long)blockIdx.x * blockDim.x + threadIdx.x;
    long row = tid >> 9;               // 512 groups of 4 cols per row (K=2048)
    int  col = (int)(tid & 511) * 4;
    const float* src;
    unsigned short* dst;
    if (row < M) {
        src = (col < I_) ? x + (size_t)row * I_ + col
                         : h + (size_t)row * H_ + (col - I_);
        dst = A + (size_t)row * K + col;
    } else {
        long r = row - M;
        src = (col < I_) ? Wx + (size_t)r * I_ + col
                         : Wh + (size_t)r * H_ + (col - I_);
        dst = W + (size_t)r * K + col;
    }
    float4 v = *(const float4*)src;
    ushort4 o;
    o.x = f2bf(v.x); o.y = f2bf(v.y); o.z = f2bf(v.z); o.w = f2bf(v.w);
    *(ushort4*)dst = o;
}

__global__ void bias_kernel(const float* __restrict__ bx, const float* __restrict__ bh,
                            float* __restrict__ bias)
{
    int i = blockIdx.x * blockDim.x + threadIdx.x;
    if (i < N) bias[i] = bx[i] + bh[i];
}

// ---------------------------------------------------------------- GEMM
// C[m][n] = sum_k A'[m][k] * W'[n][k]  (B^T layout), + bias, + activation,
// stored as bf16 gates buffer G[m][n]. 128x128 tile, BK=64, 4 waves (2x2 of
// 64x64), mfma_f32_16x16x32_bf16, global_load_lds width 16.
__global__ __launch_bounds__(256) void gemm_gates(
    const unsigned short* __restrict__ A, const unsigned short* __restrict__ W,
    const float* __restrict__ bias, __hip_bfloat16* __restrict__ G)
{
    constexpr int BM = 128, BN = 128, BK = 64;
    __shared__ __align__(16) unsigned short As[BM * BK];  // [128][64] row-major
    __shared__ __align__(16) unsigned short Ws[BN * BK];  // [128][64] row-major

    const int tid  = threadIdx.x;
    const int lane = tid & 63;
    const int wid  = tid >> 6;              // 0..3
    const int bidx = blockIdx.x;
    const int nb   = bidx & 31;             // N/BN = 32
    const int mb   = bidx >> 5;             // M/BM = 128
    const int brow = mb * BM;
    const int bcol = nb * BN;

    const int wm = (wid >> 1) * 64;         // wave sub-tile origin
    const int wn = (wid & 1) * 64;

    f32x4 acc[4][4];
#pragma unroll
    for (int m = 0; m < 4; ++m)
#pragma unroll
        for (int n = 0; n < 4; ++n) acc[m][n] = f32x4{0.f, 0.f, 0.f, 0.f};

    // staging: 16 chunks of 1 KB each per tile; chunk = 8 rows of [64] bf16.
    // wave w stages chunks {i*4 + w}. lane l -> row chunk*8 + (l>>3),
    // k-elems (l&7)*8. LDS dest base is wave-uniform; HW scatters lane*16B.
    const int srow = lane >> 3;
    const int skel = (lane & 7) * 8;

    for (int kt = 0; kt < K / BK; ++kt) {
        const int k0 = kt * BK;
#pragma unroll
        for (int i = 0; i < 4; ++i) {
            const int chunk = i * 4 + wid;
            const int r = chunk * 8 + srow;
            const unsigned short* ga = A + (size_t)(brow + r) * K + k0 + skel;
            const unsigned short* gw = W + (size_t)(bcol + r) * K + k0 + skel;
            __builtin_amdgcn_global_load_lds(
                (const __attribute__((address_space(1))) void*)ga,
                (__attribute__((address_space(3))) void*)&As[chunk * 512], 16, 0, 0);
            __builtin_amdgcn_global_load_lds(
                (const __attribute__((address_space(1))) void*)gw,
                (__attribute__((address_space(3))) void*)&Ws[chunk * 512], 16, 0, 0);
        }
        __syncthreads();   // compiler drains vmcnt before barrier

#pragma unroll
        for (int ks = 0; ks < 2; ++ks) {
            const int kb = ks * 32 + (lane >> 4) * 8;  // k-elem offset in row
            bf16x8 af[4], bw[4];
#pragma unroll
            for (int m = 0; m < 4; ++m)
                af[m] = *(const bf16x8*)&As[(wm + m * 16 + (lane & 15)) * BK + kb];
#pragma unroll
            for (int n = 0; n < 4; ++n)
                bw[n] = *(const bf16x8*)&Ws[(wn + n * 16 + (lane & 15)) * BK + kb];
#pragma unroll
            for (int m = 0; m < 4; ++m)
#pragma unroll
                for (int n = 0; n < 4; ++n)
                    acc[m][n] = __builtin_amdgcn_mfma_f32_16x16x32_bf16(
                        af[m], bw[n], acc[m][n], 0, 0, 0);
        }
        __syncthreads();   // before next tile overwrites LDS
    }

    // epilogue: bias + activation (block is entirely within one gate since
    // 1024 % 128 == 0), store bf16. C/D map: col=lane&15, row=(lane>>4)*4+j.
    const int gate  = bcol >> 10;            // 0:f 1:i 2:k 3:o
    const int crow0 = brow + wm + (lane >> 4) * 4;
    const int ccol0 = bcol + wn + (lane & 15);
#pragma unroll
    for (int n = 0; n < 4; ++n) {
        const int col = ccol0 + n * 16;
        const float bs = bias[col];
#pragma unroll
        for (int m = 0; m < 4; ++m) {
#pragma unroll
            for (int j = 0; j < 4; ++j) {
                float v = acc[m][n][j] + bs;
                float a = (gate == 2) ? tanhf(v) : 1.0f / (1.0f + __expf(-v));
                G[(size_t)(crow0 + m * 16 + j) * N + col] = __float2bfloat16(a);
            }
        }
    }
}

// ---------------------------------------------------------------- elementwise
// c_new = f*c + i*k ; h_new = o*tanh(c_new). 4 hcols per thread.
__global__ void lstm_elem(const unsigned short* __restrict__ G,
                          const float* __restrict__ c, float* __restrict__ out)
{
    long tid = (long)blockIdx.x * blockDim.x + threadIdx.x;  // B*H/4 threads
    long b   = tid >> 8;                 // 256 groups per row
    int  hc  = (int)(tid & 255) * 4;
    const unsigned short* g0 = G + (size_t)b * N;

    ushort4 fu = *(const ushort4*)(g0 + hc);
    ushort4 iu = *(const ushort4*)(g0 + 1024 + hc);
    ushort4 ku = *(const ushort4*)(g0 + 2048 + hc);
    ushort4 ou = *(const ushort4*)(g0 + 3072 + hc);
    float4  cv = *(const float4*)(c + (size_t)b * H_ + hc);

    float fv[4] = {bf2f(fu.x), bf2f(fu.y), bf2f(fu.z), bf2f(fu.w)};
    float iv[4] = {bf2f(iu.x), bf2f(iu.y), bf2f(iu.z), bf2f(iu.w)};
    float kv[4] = {bf2f(ku.x), bf2f(ku.y), bf2f(ku.z), bf2f(ku.w)};
    float ov[4] = {bf2f(ou.x), bf2f(ou.y), bf2f(ou.z), bf2f(ou.w)};
    float cc[4] = {cv.x, cv.y, cv.z, cv.w};

    float4 o4, cn4, hn4;
    float* o4p = (float*)&o4; float* cn4p = (float*)&cn4; float* hn4p = (float*)&hn4;
#pragma unroll
    for (int j = 0; j < 4; ++j) {
        float cn = fv[j] * cc[j] + iv[j] * kv[j];
        o4p[j]  = ov[j];
        cn4p[j] = cn;
        hn4p[j] = ov[j] * tanhf(cn);
    }
    const size_t base = (size_t)b * H_ + hc;
    const size_t P = (size_t)B_ * H_;
    *(float4*)(out + base)         = o4;
    *(float4*)(out + P + base)     = cn4;
    *(float4*)(out + 2 * P + base) = hn4;
}

// ---------------------------------------------------------------- launch
extern "C" void kernel_launch(void* const* d_in, const int* in_sizes, int n_in,
                              void* d_out, int out_size, void* d_ws, size_t ws_size,
                              hipStream_t stream)
{
    const float* x  = (const float*)d_in[0];
    const float* c  = (const float*)d_in[1];
    const float* h  = (const float*)d_in[2];
    const float* Wx = (const float*)d_in[3];
    const float* bx = (const float*)d_in[4];
    const float* Wh = (const float*)d_in[5];
    const float* bh = (const float*)d_in[6];

    unsigned short* Abf  = (unsigned short*)((char*)d_ws + OFF_A);
    unsigned short* Wbf  = (unsigned short*)((char*)d_ws + OFF_W);
    float*          bias = (float*)((char*)d_ws + OFF_BI);
    unsigned short* G    = (unsigned short*)((char*)d_ws + OFF_G);
    float*          out  = (float*)d_out;

    // (M+N) rows * 512 groups = 10,485,760 threads
    cvt_kernel<<<40960, 256, 0, stream>>>(x, h, Wx, Wh, Abf, Wbf);
    bias_kernel<<<16, 256, 0, stream>>>(bx, bh, bias);
    gemm_gates<<<(M / 128) * (N / 128), 256, 0, stream>>>(
        Abf, Wbf, bias, (__hip_bfloat16*)G);
    lstm_elem<<<(B_ * H_ / 4) / 256, 256, 0, stream>>>(G, c, out);
}

// Round 2
// 393.202 us; speedup vs baseline: 1.3673x; 1.3673x over previous
//
#include <hip/hip_runtime.h>
#include <hip/hip_bf16.h>
#include <cstdint>

#define DI __device__ __forceinline__

typedef __attribute__((ext_vector_type(4))) float f32x4;
typedef __attribute__((ext_vector_type(8))) short bf16x8;

static constexpr int B_ = 16384, I_ = 1024, H_ = 1024;
static constexpr int M = B_;          // 16384 rows
static constexpr int N = 4 * H_;      // 4096 gate-cols
static constexpr int K = I_ + H_;     // 2048 ([x | h])
static constexpr int NT = K / 64;     // 32 K-tiles

// workspace layout (bytes)
static constexpr size_t OFF_A  = 0;                         // M*K bf16   (64 MB)
static constexpr size_t OFF_W  = OFF_A + (size_t)M * K * 2; // N*K bf16   (16 MB)
static constexpr size_t OFF_BI = OFF_W + (size_t)N * K * 2; // N f32      (16 KB)
static constexpr size_t OFF_G  = OFF_BI + (size_t)N * 4;    // M*N bf16   (128 MB)

DI unsigned short f2bf(float f) {
    union { float f; unsigned u; } v; v.f = f;
    unsigned r = v.u + 0x7FFFu + ((v.u >> 16) & 1u);
    return (unsigned short)(r >> 16);
}
DI float bf2f(unsigned short u) {
    union { unsigned u; float f; } v; v.u = ((unsigned)u) << 16; return v.f;
}

// ---------------------------------------------------------------- convert
__global__ void cvt_kernel(const float* __restrict__ x, const float* __restrict__ h,
                           const float* __restrict__ Wx, const float* __restrict__ Wh,
                           unsigned short* __restrict__ A, unsigned short* __restrict__ W)
{
    long tid = (long)blockIdx.x * blockDim.x + threadIdx.x;
    long row = tid >> 9;
    int  col = (int)(tid & 511) * 4;
    const float* src;
    unsigned short* dst;
    if (row < M) {
        src = (col < I_) ? x + (size_t)row * I_ + col
                         : h + (size_t)row * H_ + (col - I_);
        dst = A + (size_t)row * K + col;
    } else {
        long r = row - M;
        src = (col < I_) ? Wx + (size_t)r * I_ + col
                         : Wh + (size_t)r * H_ + (col - I_);
        dst = W + (size_t)r * K + col;
    }
    float4 v = *(const float4*)src;
    ushort4 o;
    o.x = f2bf(v.x); o.y = f2bf(v.y); o.z = f2bf(v.z); o.w = f2bf(v.w);
    *(ushort4*)dst = o;
}

__global__ void bias_kernel(const float* __restrict__ bx, const float* __restrict__ bh,
                            float* __restrict__ bias)
{
    int i = blockIdx.x * blockDim.x + threadIdx.x;
    if (i < N) bias[i] = bx[i] + bh[i];
}

// ---------------------------------------------------------------- GEMM 256x256, 8-phase
// LDS tile layout: per buffer q (0/1): A at sh + q*32768 (256 rows x 64 bf16),
// B at +16384. XOR swizzle: 16B slot s stored at s ^ (row & 7). global_load_lds
// keeps LDS dest LINEAR; the swizzle is applied by permuting the per-lane
// GLOBAL source k-slot (same involution), and on the ds_read side.
DI void stage_half(const unsigned short* __restrict__ g, int grow0, int kcol,
                   unsigned short* ldsbase, int tid)
{
    const int w    = tid >> 6, lane = tid & 63;
    const int rsub = (w << 3) + (lane >> 3);                    // row within 64-row chunk
    const int kk   = kcol + (((lane & 7) ^ (lane >> 3)) << 3);  // inverse-swizzled source
#pragma unroll
    for (int l = 0; l < 2; ++l) {
        const unsigned short* gp = g + (size_t)(grow0 + (l << 6) + rsub) * K + kk;
        unsigned short* lp = ldsbase + (((l << 6) + (w << 3)) << 6);  // wave-uniform
        __builtin_amdgcn_global_load_lds(
            (const __attribute__((address_space(1))) void*)gp,
            (__attribute__((address_space(3))) void*)lp, 16, 0, 0);
    }
}

DI bf16x8 ldfrag(const unsigned short* tile, int row, int ks, int lane)
{
    const int sl = ((ks << 2) + (lane >> 4)) ^ (lane & 7);      // swizzled read slot
    return *(const bf16x8*)(tile + (row << 6) + (sl << 3));
}

DI void fbar() {
    __builtin_amdgcn_sched_barrier(0);
    __builtin_amdgcn_s_barrier();
    __builtin_amdgcn_sched_barrier(0);
}

#define MFMA_QUAD(MH, N0)                                                     \
  _Pragma("unroll") for (int m_ = 0; m_ < 4; ++m_)                            \
  _Pragma("unroll") for (int dn_ = 0; dn_ < 2; ++dn_)                         \
  _Pragma("unroll") for (int ks_ = 0; ks_ < 2; ++ks_)                         \
    acc[(MH)*4 + m_][(N0) + dn_] = __builtin_amdgcn_mfma_f32_16x16x32_bf16(   \
        a[m_][ks_], b[(N0) + dn_][ks_], acc[(MH)*4 + m_][(N0) + dn_], 0, 0, 0);

__global__ __launch_bounds__(512, 2) void gemm_gates(
    const unsigned short* __restrict__ Abf, const unsigned short* __restrict__ Wbf,
    const float* __restrict__ bias, __hip_bfloat16* __restrict__ G)
{
    __shared__ __align__(16) unsigned short sh[65536];   // 128 KiB

    const int tid  = threadIdx.x;
    const int lane = tid & 63;
    const int wid  = tid >> 6;
    const int wr   = wid >> 2;            // 0..1
    const int wc   = wid & 3;             // 0..3

    // XCD-aware block swizzle (1024 % 8 == 0 -> simple form is bijective)
    const int bid  = blockIdx.x;
    const int wg   = ((bid & 7) << 7) | (bid >> 3);
    const int nbk  = wg & 15, mbk = wg >> 4;
    const int brow = mbk << 8, bcol = nbk << 8;

    const int l15  = lane & 15;
    const int rA0  = (wr << 7) + l15;     // + m*16 (+64 for m-half1)
    const int rB0  = (wc << 6) + l15;     // + n*16

    f32x4 acc[8][4];
#pragma unroll
    for (int i = 0; i < 8; ++i)
#pragma unroll
        for (int j = 0; j < 4; ++j) acc[i][j] = f32x4{0.f, 0.f, 0.f, 0.f};
    bf16x8 a[4][2], b[4][2];

    // prologue: tile0 fully + tile1 Ah0; wait leaves tile1-Ah0 (2 loads) flying
    {
        unsigned short* A0 = sh;            // buf0 A
        unsigned short* B0 = sh + 16384;    // buf0 B
        unsigned short* A1 = sh + 32768;    // buf1 A
        stage_half(Abf, brow,       0, A0,        tid);
        stage_half(Abf, brow + 128, 0, A0 + 8192, tid);
        stage_half(Wbf, bcol,       0, B0,        tid);
        stage_half(Wbf, bcol + 128, 0, B0 + 8192, tid);
        stage_half(Abf, brow,      64, A1,        tid);
        asm volatile("s_waitcnt vmcnt(2)" ::: "memory");
        fbar();
    }

    for (int t = 0; t < NT; ++t) {
        const int q = t & 1;
        unsigned short* curA = sh + q * 32768;
        unsigned short* curB = curA + 16384;
        unsigned short* nxtA = sh + (q ^ 1) * 32768;
        unsigned short* nxtB = nxtA + 16384;
        const int k1 = (t + 1) << 6, k2 = (t + 2) << 6;

        // ---- P1: read A m-half0 (8) + B n0,n1 (4); stage Ah1(t+1)
#pragma unroll
        for (int m = 0; m < 4; ++m)
#pragma unroll
            for (int ks = 0; ks < 2; ++ks)
                a[m][ks] = ldfrag(curA, rA0 + m * 16, ks, lane);
#pragma unroll
        for (int n = 0; n < 2; ++n)
#pragma unroll
            for (int ks = 0; ks < 2; ++ks)
                b[n][ks] = ldfrag(curB, rB0 + n * 16, ks, lane);
        if (t + 1 < NT) stage_half(Abf, brow + 128, k1, nxtA + 8192, tid);
        fbar();
        __builtin_amdgcn_s_setprio(1);
        MFMA_QUAD(0, 0);
        __builtin_amdgcn_s_setprio(0);
        fbar();

        // ---- P2: read B n2,n3 (4); stage Bh0(t+1)
#pragma unroll
        for (int n = 2; n < 4; ++n)
#pragma unroll
            for (int ks = 0; ks < 2; ++ks)
                b[n][ks] = ldfrag(curB, rB0 + n * 16, ks, lane);
        if (t + 1 < NT) stage_half(Wbf, bcol, k1, nxtB, tid);
        fbar();
        __builtin_amdgcn_s_setprio(1);
        MFMA_QUAD(0, 2);
        __builtin_amdgcn_s_setprio(0);
        fbar();

        // ---- P3: read A m-half1 (8); stage Bh1(t+1)
#pragma unroll
        for (int m = 0; m < 4; ++m)
#pragma unroll
            for (int ks = 0; ks < 2; ++ks)
                a[m][ks] = ldfrag(curA, rA0 + 64 + m * 16, ks, lane);
        if (t + 1 < NT) stage_half(Wbf, bcol + 128, k1, nxtB + 8192, tid);
        fbar();
        __builtin_amdgcn_s_setprio(1);
        MFMA_QUAD(1, 2);
        __builtin_amdgcn_s_setprio(0);
        fbar();

        // ---- P4: no ds reads; stage Ah0(t+2) into CURRENT buf (region free
        // after P3's barrier); counted wait -> tile t+1 fully landed, t+2's
        // Ah0 (2 loads) stays in flight across the tile boundary.
        if (t + 2 < NT) {
            stage_half(Abf, brow, k2, curA, tid);
            asm volatile("s_waitcnt vmcnt(2)" ::: "memory");
        } else {
            asm volatile("s_waitcnt vmcnt(0)" ::: "memory");
        }
        fbar();
        __builtin_amdgcn_s_setprio(1);
        MFMA_QUAD(1, 0);
        __builtin_amdgcn_s_setprio(0);
        fbar();
    }

    // epilogue: bias + activation, scalar bf16 stores (block is within one gate)
    const int gate  = bcol >> 10;
    const int crow0 = brow + (wr << 7) + ((lane >> 4) << 2);
    const int ccol0 = bcol + (wc << 6) + l15;
#pragma unroll
    for (int n = 0; n < 4; ++n) {
        const int col = ccol0 + n * 16;
        const float bs = bias[col];
#pragma unroll
        for (int mf = 0; mf < 8; ++mf) {
#pragma unroll
            for (int j = 0; j < 4; ++j) {
                float v = acc[mf][n][j] + bs;
                float r;
                if (gate == 2) {
                    float vc = fminf(fmaxf(v, -15.f), 15.f);
                    float e  = __expf(2.f * vc);
                    r = (e - 1.f) / (e + 1.f);
                } else {
                    r = 1.f / (1.f + __expf(-v));
                }
                G[(size_t)(crow0 + mf * 16 + j) * N + col] = __float2bfloat16(r);
            }
        }
    }
}

// ---------------------------------------------------------------- elementwise
__global__ void lstm_elem(const unsigned short* __restrict__ G,
                          const float* __restrict__ c, float* __restrict__ out)
{
    long tid = (long)blockIdx.x * blockDim.x + threadIdx.x;
    long bq  = tid >> 8;
    int  hc  = (int)(tid & 255) * 4;
    const unsigned short* g0 = G + (size_t)bq * N;

    ushort4 fu = *(const ushort4*)(g0 + hc);
    ushort4 iu = *(const ushort4*)(g0 + 1024 + hc);
    ushort4 ku = *(const ushort4*)(g0 + 2048 + hc);
    ushort4 ou = *(const ushort4*)(g0 + 3072 + hc);
    float4  cv = *(const float4*)(c + (size_t)bq * H_ + hc);

    float fv[4] = {bf2f(fu.x), bf2f(fu.y), bf2f(fu.z), bf2f(fu.w)};
    float iv[4] = {bf2f(iu.x), bf2f(iu.y), bf2f(iu.z), bf2f(iu.w)};
    float kv[4] = {bf2f(ku.x), bf2f(ku.y), bf2f(ku.z), bf2f(ku.w)};
    float ov[4] = {bf2f(ou.x), bf2f(ou.y), bf2f(ou.z), bf2f(ou.w)};
    float cc[4] = {cv.x, cv.y, cv.z, cv.w};

    float4 o4, cn4, hn4;
    float* o4p = (float*)&o4; float* cn4p = (float*)&cn4; float* hn4p = (float*)&hn4;
#pragma unroll
    for (int j = 0; j < 4; ++j) {
        float cn = fv[j] * cc[j] + iv[j] * kv[j];
        o4p[j]  = ov[j];
        cn4p[j] = cn;
        hn4p[j] = ov[j] * tanhf(cn);
    }
    const size_t base = (size_t)bq * H_ + hc;
    const size_t P = (size_t)B_ * H_;
    *(float4*)(out + base)         = o4;
    *(float4*)(out + P + base)     = cn4;
    *(float4*)(out + 2 * P + base) = hn4;
}

// ---------------------------------------------------------------- launch
extern "C" void kernel_launch(void* const* d_in, const int* in_sizes, int n_in,
                              void* d_out, int out_size, void* d_ws, size_t ws_size,
                              hipStream_t stream)
{
    const float* x  = (const float*)d_in[0];
    const float* c  = (const float*)d_in[1];
    const float* h  = (const float*)d_in[2];
    const float* Wx = (const float*)d_in[3];
    const float* bx = (const float*)d_in[4];
    const float* Wh = (const float*)d_in[5];
    const float* bh = (const float*)d_in[6];

    unsigned short* Abf  = (unsigned short*)((char*)d_ws + OFF_A);
    unsigned short* Wbf  = (unsigned short*)((char*)d_ws + OFF_W);
    float*          bias = (float*)((char*)d_ws + OFF_BI);
    unsigned short* G    = (unsigned short*)((char*)d_ws + OFF_G);
    float*          out  = (float*)d_out;

    cvt_kernel<<<40960, 256, 0, stream>>>(x, h, Wx, Wh, Abf, Wbf);
    bias_kernel<<<16, 256, 0, stream>>>(bx, bh, bias);
    gemm_gates<<<(M / 256) * (N / 256), 512, 0, stream>>>(
        Abf, Wbf, bias, (__hip_bfloat16*)G);
    lstm_elem<<<(B_ * H_ / 4) / 256, 256, 0, stream>>>(G, c, out);
}

// Round 3
// 332.650 us; speedup vs baseline: 1.6162x; 1.1820x over previous
//
#include <hip/hip_runtime.h>
#include <hip/hip_bf16.h>
#include <cstdint>

#define DI __device__ __forceinline__

typedef __attribute__((ext_vector_type(4))) float f32x4;
typedef __attribute__((ext_vector_type(8))) short bf16x8;

static constexpr int B_ = 16384, I_ = 1024, H_ = 1024;
static constexpr int M = B_;          // 16384 rows
static constexpr int N = 4 * H_;      // 4096 gate-cols (permuted: see cvt)
static constexpr int K = I_ + H_;     // 2048 ([x | h])
static constexpr int NT = K / 64;     // 32 K-tiles

// workspace layout (bytes)
static constexpr size_t OFF_A  = 0;                         // M*K bf16   (64 MB)
static constexpr size_t OFF_W  = OFF_A + (size_t)M * K * 2; // N*K bf16   (16 MB)
static constexpr size_t OFF_BI = OFF_W + (size_t)N * K * 2; // N f32      (16 KB)

DI unsigned short f2bf(float f) {
    union { float f; unsigned u; } v; v.f = f;
    unsigned r = v.u + 0x7FFFu + ((v.u >> 16) & 1u);
    return (unsigned short)(r >> 16);
}

// ---------------------------------------------------------------- convert
// A' = [x | h] (M x K) bf16. W' rows PERMUTED so that GEMM col
// r = g64*64 + gate*16 + l15 maps to (gate, hcol = g64*16 + l15):
// all 4 gates of one h-col land 16 apart = the MFMA n-fragment stride.
__global__ void cvt_kernel(const float* __restrict__ x, const float* __restrict__ h,
                           const float* __restrict__ Wx, const float* __restrict__ Wh,
                           unsigned short* __restrict__ A, unsigned short* __restrict__ W)
{
    long tid = (long)blockIdx.x * blockDim.x + threadIdx.x;
    long row = tid >> 9;
    int  col = (int)(tid & 511) * 4;
    const float* src;
    unsigned short* dst;
    if (row < M) {
        src = (col < I_) ? x + (size_t)row * I_ + col
                         : h + (size_t)row * H_ + (col - I_);
        dst = A + (size_t)row * K + col;
    } else {
        int r = (int)(row - M);                 // dst row in W'
        int gate = (r >> 4) & 3;
        int hcol = ((r >> 6) << 4) | (r & 15);
        int srow = gate * H_ + hcol;            // src row in [4,H] stack
        src = (col < I_) ? Wx + (size_t)srow * I_ + col
                         : Wh + (size_t)srow * H_ + (col - I_);
        dst = W + (size_t)r * K + col;
    }
    float4 v = *(const float4*)src;
    ushort4 o;
    o.x = f2bf(v.x); o.y = f2bf(v.y); o.z = f2bf(v.z); o.w = f2bf(v.w);
    *(ushort4*)dst = o;
}

__global__ void bias_kernel(const float* __restrict__ bx, const float* __restrict__ bh,
                            float* __restrict__ bias)
{
    int r = blockIdx.x * blockDim.x + threadIdx.x;
    if (r < N) {
        int gate = (r >> 4) & 3;
        int hcol = ((r >> 6) << 4) | (r & 15);
        int s = gate * H_ + hcol;
        bias[r] = bx[s] + bh[s];
    }
}

// ---------------------------------------------------------------- GEMM 256x256, 8-phase
// Same verified K-loop as round 2 (swizzled LDS, counted vmcnt, setprio).
// Epilogue now computes the full LSTM cell: acc[mf][n][j] with n = gate
// (0:f 1:i 2:k 3:o) for one h-col per lane -> writes o, c_new, h_new fp32.
DI void stage_half(const unsigned short* __restrict__ g, int grow0, int kcol,
                   unsigned short* ldsbase, int tid)
{
    const int w    = tid >> 6, lane = tid & 63;
    const int rsub = (w << 3) + (lane >> 3);
    const int kk   = kcol + (((lane & 7) ^ (lane >> 3)) << 3);  // inverse-swizzled src
#pragma unroll
    for (int l = 0; l < 2; ++l) {
        const unsigned short* gp = g + (size_t)(grow0 + (l << 6) + rsub) * K + kk;
        unsigned short* lp = ldsbase + (((l << 6) + (w << 3)) << 6);
        __builtin_amdgcn_global_load_lds(
            (const __attribute__((address_space(1))) void*)gp,
            (__attribute__((address_space(3))) void*)lp, 16, 0, 0);
    }
}

DI bf16x8 ldfrag(const unsigned short* tile, int row, int ks, int lane)
{
    const int sl = ((ks << 2) + (lane >> 4)) ^ (lane & 7);
    return *(const bf16x8*)(tile + (row << 6) + (sl << 3));
}

DI void fbar() {
    __builtin_amdgcn_sched_barrier(0);
    __builtin_amdgcn_s_barrier();
    __builtin_amdgcn_sched_barrier(0);
}

DI float sigf(float v) { return 1.f / (1.f + __expf(-v)); }
DI float tanhfast(float v) {
    float vc = fminf(fmaxf(v, -15.f), 15.f);
    float e  = __expf(2.f * vc);
    return (e - 1.f) / (e + 1.f);
}

#define MFMA_QUAD(MH, N0)                                                     \
  _Pragma("unroll") for (int m_ = 0; m_ < 4; ++m_)                            \
  _Pragma("unroll") for (int dn_ = 0; dn_ < 2; ++dn_)                         \
  _Pragma("unroll") for (int ks_ = 0; ks_ < 2; ++ks_)                         \
    acc[(MH)*4 + m_][(N0) + dn_] = __builtin_amdgcn_mfma_f32_16x16x32_bf16(   \
        a[m_][ks_], b[(N0) + dn_][ks_], acc[(MH)*4 + m_][(N0) + dn_], 0, 0, 0);

__global__ __launch_bounds__(512, 2) void gemm_lstm(
    const unsigned short* __restrict__ Abf, const unsigned short* __restrict__ Wbf,
    const float* __restrict__ bias, const float* __restrict__ c,
    float* __restrict__ out)
{
    __shared__ __align__(16) unsigned short sh[65536];   // 128 KiB

    const int tid  = threadIdx.x;
    const int lane = tid & 63;
    const int wid  = tid >> 6;
    const int wr   = wid >> 2;            // 0..1
    const int wc   = wid & 3;             // 0..3

    const int bid  = blockIdx.x;
    const int wg   = ((bid & 7) << 7) | (bid >> 3);   // XCD swizzle (1024%8==0)
    const int nbk  = wg & 15, mbk = wg >> 4;
    const int brow = mbk << 8, bcol = nbk << 8;

    const int l15  = lane & 15;
    const int rA0  = (wr << 7) + l15;
    const int rB0  = (wc << 6) + l15;

    f32x4 acc[8][4];
#pragma unroll
    for (int i = 0; i < 8; ++i)
#pragma unroll
        for (int j = 0; j < 4; ++j) acc[i][j] = f32x4{0.f, 0.f, 0.f, 0.f};
    bf16x8 a[4][2], b[4][2];

    // prologue: tile0 fully + tile1 Ah0; wait leaves tile1-Ah0 (2 loads) flying
    {
        unsigned short* A0 = sh;
        unsigned short* B0 = sh + 16384;
        unsigned short* A1 = sh + 32768;
        stage_half(Abf, brow,       0, A0,        tid);
        stage_half(Abf, brow + 128, 0, A0 + 8192, tid);
        stage_half(Wbf, bcol,       0, B0,        tid);
        stage_half(Wbf, bcol + 128, 0, B0 + 8192, tid);
        stage_half(Abf, brow,      64, A1,        tid);
        asm volatile("s_waitcnt vmcnt(2)" ::: "memory");
        fbar();
    }

    for (int t = 0; t < NT; ++t) {
        const int q = t & 1;
        unsigned short* curA = sh + q * 32768;
        unsigned short* curB = curA + 16384;
        unsigned short* nxtA = sh + (q ^ 1) * 32768;
        unsigned short* nxtB = nxtA + 16384;
        const int k1 = (t + 1) << 6, k2 = (t + 2) << 6;

        // ---- P1: read A m-half0 (8) + B n0,n1 (4); stage Ah1(t+1)
#pragma unroll
        for (int m = 0; m < 4; ++m)
#pragma unroll
            for (int ks = 0; ks < 2; ++ks)
                a[m][ks] = ldfrag(curA, rA0 + m * 16, ks, lane);
#pragma unroll
        for (int n = 0; n < 2; ++n)
#pragma unroll
            for (int ks = 0; ks < 2; ++ks)
                b[n][ks] = ldfrag(curB, rB0 + n * 16, ks, lane);
        if (t + 1 < NT) stage_half(Abf, brow + 128, k1, nxtA + 8192, tid);
        fbar();
        __builtin_amdgcn_s_setprio(1);
        MFMA_QUAD(0, 0);
        __builtin_amdgcn_s_setprio(0);
        fbar();

        // ---- P2: read B n2,n3 (4); stage Bh0(t+1)
#pragma unroll
        for (int n = 2; n < 4; ++n)
#pragma unroll
            for (int ks = 0; ks < 2; ++ks)
                b[n][ks] = ldfrag(curB, rB0 + n * 16, ks, lane);
        if (t + 1 < NT) stage_half(Wbf, bcol, k1, nxtB, tid);
        fbar();
        __builtin_amdgcn_s_setprio(1);
        MFMA_QUAD(0, 2);
        __builtin_amdgcn_s_setprio(0);
        fbar();

        // ---- P3: read A m-half1 (8); stage Bh1(t+1)
#pragma unroll
        for (int m = 0; m < 4; ++m)
#pragma unroll
            for (int ks = 0; ks < 2; ++ks)
                a[m][ks] = ldfrag(curA, rA0 + 64 + m * 16, ks, lane);
        if (t + 1 < NT) stage_half(Wbf, bcol + 128, k1, nxtB + 8192, tid);
        fbar();
        __builtin_amdgcn_s_setprio(1);
        MFMA_QUAD(1, 2);
        __builtin_amdgcn_s_setprio(0);
        fbar();

        // ---- P4: stage Ah0(t+2) into CURRENT buf; counted wait
        if (t + 2 < NT) {
            stage_half(Abf, brow, k2, curA, tid);
            asm volatile("s_waitcnt vmcnt(2)" ::: "memory");
        } else {
            asm volatile("s_waitcnt vmcnt(0)" ::: "memory");
        }
        fbar();
        __builtin_amdgcn_s_setprio(1);
        MFMA_QUAD(1, 0);
        __builtin_amdgcn_s_setprio(0);
        fbar();
    }

    // ---- fused LSTM epilogue: n-index = gate for one h-col per lane
    const int hcol  = (((nbk << 2) + wc) << 4) + l15;
    const int crow0 = brow + (wr << 7) + ((lane >> 4) << 2);
    const int cb0   = bcol + (wc << 6) + l15;
    const float bs0 = bias[cb0];
    const float bs1 = bias[cb0 + 16];
    const float bs2 = bias[cb0 + 32];
    const float bs3 = bias[cb0 + 48];
    const size_t P  = (size_t)B_ * H_;
#pragma unroll
    for (int mf = 0; mf < 8; ++mf) {
#pragma unroll
        for (int j = 0; j < 4; ++j) {
            const int row = crow0 + mf * 16 + j;
            const size_t base = (size_t)row * H_ + hcol;
            float fg = sigf(acc[mf][0][j] + bs0);
            float ig = sigf(acc[mf][1][j] + bs1);
            float kg = tanhfast(acc[mf][2][j] + bs2);
            float og = sigf(acc[mf][3][j] + bs3);
            float cv = c[base];
            float cn = fg * cv + ig * kg;
            float hn = og * tanhfast(cn);
            out[base]         = og;
            out[P + base]     = cn;
            out[2 * P + base] = hn;
        }
    }
}

// ---------------------------------------------------------------- launch
extern "C" void kernel_launch(void* const* d_in, const int* in_sizes, int n_in,
                              void* d_out, int out_size, void* d_ws, size_t ws_size,
                              hipStream_t stream)
{
    const float* x  = (const float*)d_in[0];
    const float* c  = (const float*)d_in[1];
    const float* h  = (const float*)d_in[2];
    const float* Wx = (const float*)d_in[3];
    const float* bx = (const float*)d_in[4];
    const float* Wh = (const float*)d_in[5];
    const float* bh = (const float*)d_in[6];

    unsigned short* Abf  = (unsigned short*)((char*)d_ws + OFF_A);
    unsigned short* Wbf  = (unsigned short*)((char*)d_ws + OFF_W);
    float*          bias = (float*)((char*)d_ws + OFF_BI);
    float*          out  = (float*)d_out;

    cvt_kernel<<<40960, 256, 0, stream>>>(x, h, Wx, Wh, Abf, Wbf);
    bias_kernel<<<16, 256, 0, stream>>>(bx, bh, bias);
    gemm_lstm<<<(M / 256) * (N / 256), 512, 0, stream>>>(
        Abf, Wbf, bias, c, out);
}